// Round 1
// 250.410 us; speedup vs baseline: 1.0075x; 1.0075x over previous
//
#include <hip/hip_runtime.h>
#include <hip/hip_bf16.h>
#include <math.h>

#define BB 8
#define NN 512
#define DD 512
#define NH 16
#define DH 32
#define TD 1536
#define NG 32
#define MAXD 128

typedef __attribute__((ext_vector_type(8))) short bf16x8;
typedef __attribute__((ext_vector_type(4))) float f32x4;
typedef __attribute__((ext_vector_type(2))) unsigned int u32x2;
typedef __attribute__((ext_vector_type(4))) unsigned int u32x4;

__device__ inline short f2bf(float x) {
    __hip_bfloat16 h = __float2bfloat16(x);
    return *reinterpret_cast<short*>(&h);
}
__device__ inline float bf2f(short x) {
    union { unsigned u; float f; } c;
    c.u = ((unsigned)(unsigned short)x) << 16;
    return c.f;
}

// async 16B global->LDS. lds dest must be WAVE-UNIFORM base; lane i lands at base + i*16.
__device__ inline void gld_lds16(const void* g, void* l) {
    __builtin_amdgcn_global_load_lds(
        (const __attribute__((address_space(1))) unsigned int*)g,
        (__attribute__((address_space(3))) unsigned int*)l, 16, 0, 0);
}

// ------- weight fp32 -> bf16 convert (4 arrays) + fused RBF bias table ------
// Table: 193 nodes on [0,20] (nearest-neighbor lookup; |f'|*delta/2 ~ 3e-3).
__global__ __launch_bounds__(256) void cvt_weights(
    const float* __restrict__ s0, const float* __restrict__ s1,
    const float* __restrict__ s2, const float* __restrict__ s3,
    short* __restrict__ d0, short* __restrict__ d1,
    short* __restrict__ d2, short* __restrict__ d3,
    const float* __restrict__ rbfw, const float* __restrict__ rbfb,
    short* __restrict__ Tg,
    int n0, int n1, int n2, int n3) {
    if (blockIdx.y == 4) {
        if (blockIdx.x != 0) return;
        const float STEP  = 20.0f / 31.0f;
        const float COEFF = -0.5f / (STEP * STEP);
        for (int idx = threadIdx.x; idx < 194 * 16; idx += 256) {
            const int i = idx >> 4, h = idx & 15;
            const float x = fminf((float)i, 192.0f) * (20.0f / 192.0f);
            float acc = rbfb[h];
#pragma unroll
            for (int g = 0; g < NG; g++) {
                const float t = x - (float)g * STEP;
                acc += __expf(COEFF * t * t) * rbfw[h * NG + g];
            }
            Tg[idx] = f2bf(acc);
        }
        return;
    }
    const float* s; short* d; int n;
    switch (blockIdx.y) {
        case 0: s = s0; d = d0; n = n0; break;
        case 1: s = s1; d = d1; n = n1; break;
        case 2: s = s2; d = d2; n = n2; break;
        default: s = s3; d = d3; n = n3; break;
    }
    const int i = (blockIdx.x * 256 + threadIdx.x) * 4;
    if (i >= n) return;
    const float4 v = *(const float4*)(s + i);
    short4 o;
    o.x = f2bf(v.x); o.y = f2bf(v.y); o.z = f2bf(v.z); o.w = f2bf(v.w);
    *(short4*)(d + i) = o;
}

// ---------------- LayerNorm: bf16 out ----------------
__global__ __launch_bounds__(256) void ln_kernel(const float* __restrict__ x,
                                                 const float* __restrict__ g,
                                                 const float* __restrict__ b,
                                                 short* __restrict__ out_bf) {
    const int row = blockIdx.x;
    const int tid = threadIdx.x;
    const int wave = tid >> 6, lane = tid & 63;
    const float* xr = x + (size_t)row * DD;
    const float v0 = xr[tid], v1 = xr[tid + 256];
    float s = v0 + v1, q = v0 * v0 + v1 * v1;
#pragma unroll
    for (int m = 1; m < 64; m <<= 1) { s += __shfl_xor(s, m); q += __shfl_xor(q, m); }
    __shared__ float ps[8];
    if (lane == 0) { ps[wave] = s; ps[wave + 4] = q; }
    __syncthreads();
    s = ps[0] + ps[1] + ps[2] + ps[3];
    q = ps[4] + ps[5] + ps[6] + ps[7];
    const float mean = s * (1.0f / DD);
    const float var  = q * (1.0f / DD) - mean * mean;
    const float rs   = rsqrtf(var + 1e-5f);
    out_bf[(size_t)row * DD + tid]       = f2bf((v0 - mean) * rs * g[tid] + b[tid]);
    out_bf[(size_t)row * DD + tid + 256] = f2bf((v1 - mean) * rs * g[tid + 256] + b[tid + 256]);
}

// ------- bf16 MFMA GEMM, double-buffered: C = A @ W^T + bias (+gelu)(+res) --
template <int TM, bool GELU, bool RES, bool OUTBF>
__global__ __launch_bounds__(256) void gemm_bf16(
    const short* __restrict__ A, const short* __restrict__ Bw,
    const float* __restrict__ bias, const float* __restrict__ res,
    void* __restrict__ Cout, int M, int Nout, int K) {
    const int MI = TM / 32;
    const int bm = blockIdx.y * TM;
    const int bn = blockIdx.x * 128;
    const int tid  = threadIdx.x;
    const int wave = tid >> 6;
    const int lane = tid & 63;
    const int l16  = lane & 15;
    const int quad = lane >> 4;
    const int wr = (wave >> 1) * (TM / 2);
    const int wc = (wave & 1) * 64;

    __shared__ short As[2][TM * 32];
    __shared__ short Bs[2][128 * 32];

    f32x4 acc[MI][4];
#pragma unroll
    for (int i = 0; i < MI; i++)
#pragma unroll
        for (int j = 0; j < 4; j++) acc[i][j] = (f32x4){0.f, 0.f, 0.f, 0.f};

    auto stage = [&](int buf, int k0) {
        const short* Ab = A + (size_t)bm * K + k0;
        const short* Bb = Bw + (size_t)bn * K + k0;
#pragma unroll
        for (int j = 0; j < TM / 64; j++) {
            const int idx = j * 256 + wave * 64 + lane;
            gld_lds16(Ab + (size_t)(idx >> 2) * K + (idx & 3) * 8,
                      &As[buf][(size_t)(j * 256 + wave * 64) * 8]);
        }
#pragma unroll
        for (int j = 0; j < 2; j++) {
            const int idx = j * 256 + wave * 64 + lane;
            gld_lds16(Bb + (size_t)(idx >> 2) * K + (idx & 3) * 8,
                      &Bs[buf][(size_t)(j * 256 + wave * 64) * 8]);
        }
    };
    auto compute = [&](int buf) {
        bf16x8 af[MI], bfr[4];
#pragma unroll
        for (int i = 0; i < MI; i++)
            af[i] = *(const bf16x8*)&As[buf][(wr + i * 16 + l16) * 32 + quad * 8];
#pragma unroll
        for (int j = 0; j < 4; j++)
            bfr[j] = *(const bf16x8*)&Bs[buf][(wc + j * 16 + l16) * 32 + quad * 8];
#pragma unroll
        for (int i = 0; i < MI; i++)
#pragma unroll
            for (int j = 0; j < 4; j++)
                acc[i][j] = __builtin_amdgcn_mfma_f32_16x16x32_bf16(af[i], bfr[j], acc[i][j], 0, 0, 0);
    };

    stage(0, 0);
    __syncthreads();
    int cur = 0;
    for (int k0 = 32; k0 < K; k0 += 32) {
        stage(cur ^ 1, k0);
        compute(cur);
        __syncthreads();
        cur ^= 1;
    }
    compute(cur);

#pragma unroll
    for (int i = 0; i < MI; i++) {
#pragma unroll
        for (int r = 0; r < 4; r++) {
            const int row = bm + wr + i * 16 + quad * 4 + r;
#pragma unroll
            for (int j = 0; j < 4; j++) {
                const int col = bn + wc + j * 16 + l16;
                float v = acc[i][j][r] + bias[col];
                if (GELU) v = 0.5f * v * (1.0f + erff(v * 0.70710678118654752f));
                if (RES)  v += res[(size_t)row * Nout + col];
                if (OUTBF) ((short*)Cout)[(size_t)row * Nout + col] = f2bf(v);
                else       ((float*)Cout)[(size_t)row * Nout + col] = v;
            }
        }
    }
}

// ------- out-proj GEMM with FUSED split-K combine on the A operand ---------
__global__ __launch_bounds__(256) void gemm_op(
    const short* __restrict__ Opart,   // [3][4096][512] bf16 unnormalized
    const float* __restrict__ lpart,   // [3][4096][16] fp32
    const short* __restrict__ Bw,      // wo_bf [512][512]
    const float* __restrict__ bias,    // bo
    const short* __restrict__ resb,    // h_bf bf16 [4096][512]
    float* __restrict__ Cout) {        // hres fp32
    const int bm = blockIdx.y * 64;
    const int bn = blockIdx.x * 128;
    const int tid  = threadIdx.x;
    const int wave = tid >> 6;
    const int lane = tid & 63;
    const int l16  = lane & 15;
    const int quad = lane >> 4;
    const int wr = (wave >> 1) * 32;
    const int wc = (wave & 1) * 64;
    const size_t PO = (size_t)4096 * 512;

    __shared__ short As[2][64 * 32];
    __shared__ short Bs[2][128 * 32];
    __shared__ float Lr[64 * 16];

    for (int i = tid; i < 64 * 16; i += 256) {
        const int idx = (bm + (i >> 4)) * 16 + (i & 15);
        Lr[i] = 1.0f / (lpart[idx] + lpart[4096 * 16 + idx] + lpart[2 * 4096 * 16 + idx]);
    }
    __syncthreads();

    f32x4 acc[2][4];
#pragma unroll
    for (int i = 0; i < 2; i++)
#pragma unroll
        for (int j = 0; j < 4; j++) acc[i][j] = (f32x4){0.f, 0.f, 0.f, 0.f};

    const int arow = tid >> 2;
    const int acb  = (tid & 3) * 8;

    auto stageA = [&](int buf, int k0) {
        const size_t base = (size_t)(bm + arow) * 512 + k0 + acb;
        const bf16x8 a0 = *(const bf16x8*)(Opart + base);
        const bf16x8 a1 = *(const bf16x8*)(Opart + PO + base);
        const bf16x8 a2 = *(const bf16x8*)(Opart + 2 * PO + base);
        const float rv = Lr[arow * 16 + (k0 >> 5)];
        bf16x8 o;
#pragma unroll
        for (int e = 0; e < 8; e++)
            o[e] = f2bf((bf2f(a0[e]) + bf2f(a1[e]) + bf2f(a2[e])) * rv);
        *(bf16x8*)&As[buf][arow * 32 + acb] = o;
    };
    auto stageB = [&](int buf, int k0) {
        const short* Bb = Bw + (size_t)bn * 512 + k0;
#pragma unroll
        for (int j = 0; j < 2; j++) {
            const int idx = j * 256 + wave * 64 + lane;
            gld_lds16(Bb + (size_t)(idx >> 2) * 512 + (idx & 3) * 8,
                      &Bs[buf][(size_t)(j * 256 + wave * 64) * 8]);
        }
    };
    auto compute = [&](int buf) {
        bf16x8 af[2], bfr[4];
#pragma unroll
        for (int i = 0; i < 2; i++)
            af[i] = *(const bf16x8*)&As[buf][(wr + i * 16 + l16) * 32 + quad * 8];
#pragma unroll
        for (int j = 0; j < 4; j++)
            bfr[j] = *(const bf16x8*)&Bs[buf][(wc + j * 16 + l16) * 32 + quad * 8];
#pragma unroll
        for (int i = 0; i < 2; i++)
#pragma unroll
            for (int j = 0; j < 4; j++)
                acc[i][j] = __builtin_amdgcn_mfma_f32_16x16x32_bf16(af[i], bfr[j], acc[i][j], 0, 0, 0);
    };

    stageB(0, 0);
    stageA(0, 0);
    __syncthreads();
    int cur = 0;
    for (int k0 = 32; k0 < 512; k0 += 32) {
        stageB(cur ^ 1, k0);
        stageA(cur ^ 1, k0);
        compute(cur);
        __syncthreads();
        cur ^= 1;
    }
    compute(cur);

#pragma unroll
    for (int i = 0; i < 2; i++) {
#pragma unroll
        for (int r = 0; r < 4; r++) {
            const int row = bm + wr + i * 16 + quad * 4 + r;
#pragma unroll
            for (int j = 0; j < 4; j++) {
                const int col = bn + wc + j * 16 + l16;
                float v = acc[i][j][r] + bias[col] + bf2f(resb[(size_t)row * 512 + col]);
                Cout[(size_t)row * 512 + col] = v;
            }
        }
    }
}

// ---------------- MFMA flash attention, 3-way split-K, NN-table bias --------
// v2: K fragments direct global->reg (no Kc, no 8-way b128 conflicts);
//     V via ds_read_b64_tr_b16 + v_perm repack (kills 32x 4-way ds_read_u16);
//     V double-buffered LDS + 1-deep DMA/K prefetch pipeline;
//     (dc,ii) bias indices precomputed once per block into packed u16 LDS
//     (was recomputed 8x, one per wave, with 8 global loads per chunk);
//     paired-head table lookups as single u32; Pb stride-40 (2-way banks).
__global__ __launch_bounds__(512, 4) void attn_mfma(
    const short* __restrict__ qkv,
    const int* __restrict__ dist,
    const float* __restrict__ dist3d,
    const float* __restrict__ demb,
    const short* __restrict__ Tg,
    short* __restrict__ O_part,        // [3][4096][512] bf16 unnormalized
    float* __restrict__ l_part)        // [3][4096][16]  fp32
{
    const int blk  = blockIdx.x;
    const int b    = blk & 7;
    const int t3   = blk >> 3;
    const int part = t3 % 3;
    const int q0   = (t3 / 3) * 16;
    const int tid  = threadIdx.x;
    const int wave = tid >> 6;
    const int lane = tid & 63;
    const int l16  = lane & 15;
    const int quad = lane >> 4;
    const int hh0  = wave * 2;

    const int cbeg = part * 11;
    const int cend = (part == 2) ? 32 : cbeg + 11;
    const int kbeg = cbeg * 16;
    const int kcnt = (cend - cbeg) * 16;   // 176 or 160

    __shared__ short Vc[2][NH * 16 * 32];   // 32 KB dbuf, DMA-linear [h][16k][32c]
    __shared__ short Pb[8 * 16 * 40];       // 10 KB, stride-40 pad -> <=2-way banks
    __shared__ short Tt[194 * 18];          // rbf NN table, stride-18 pad
    __shared__ short Db[128 * 18];          // dist_emb, stride-18 pad
    __shared__ unsigned short Pk[16 * 178]; // packed dc | (ii<<8), stride-178 pad

    for (int i = tid; i < 8 * 16 * 40; i += 512) Pb[i] = 0;
    for (int i = tid; i < 194 * 16; i += 512) Tt[(i >> 4) * 18 + (i & 15)] = Tg[i];
    for (int i = tid; i < 128 * 16; i += 512) Db[(i >> 4) * 18 + (i & 15)] = f2bf(demb[i]);
    {   // shared (dc, ii) precompute: 32 threads per q-row, coalesced rows
        const int q  = tid >> 5;
        const int kl = tid & 31;
        const size_t rb = ((size_t)(b * NN) + q0 + q) * NN + kbeg;
        for (int k = kl; k < kcnt; k += 32) {
            int dc = dist[rb + k];
            dc = min(max(dc, 0), MAXD - 1);
            int ii = (int)(dist3d[rb + k] * 9.6f + 0.5f);  // 192/20
            ii = min(ii, 192);
            Pk[q * 178 + k] = (unsigned short)(dc | (ii << 8));
        }
    }

    const float scale = 0.17677669529663687f;
    bf16x8 qf[2];
#pragma unroll
    for (int h = 0; h < 2; h++)
        qf[h] = *(const bf16x8*)(qkv + (size_t)(b * NN + q0 + l16) * TD + (hh0 + h) * DH + quad * 8);

    f32x4 O[2][2];
    float lsum[2][4];
#pragma unroll
    for (int h = 0; h < 2; h++) {
#pragma unroll
        for (int tt = 0; tt < 2; tt++) O[h][tt] = (f32x4){0.f, 0.f, 0.f, 0.f};
#pragma unroll
        for (int r = 0; r < 4; r++) lsum[h][r] = 0.f;
    }

    __syncthreads();  // tables + Pk + Pb-zero visible; last barrier.

    const int sk = lane >> 2;
    const int sc = lane & 3;

    auto stageV = [&](int buf, int c) {
        const size_t rowb = (size_t)(b * NN + c * 16 + sk) * TD + 2 * DD + sc * 8;
#pragma unroll
        for (int h = 0; h < 2; h++)
            gld_lds16(qkv + rowb + (hh0 + h) * DH, &Vc[buf][(hh0 + h) * 512]);
    };
    auto loadK = [&](int c, bf16x8* kd) {
#pragma unroll
        for (int h = 0; h < 2; h++)
            kd[h] = *(const bf16x8*)(qkv + (size_t)(b * NN + c * 16 + l16) * TD + DD + (hh0 + h) * DH + quad * 8);
    };

    bf16x8 kf[2], kfn[2];
    stageV(0, cbeg);
    loadK(cbeg, kf);
    int cur = 0;

    for (int c = cbeg; c < cend; c++) {
        asm volatile("" ::: "memory");
        __builtin_amdgcn_s_waitcnt(0x0F70);  // vmcnt(0): V(c) in LDS, kf(c) in regs
        asm volatile("" ::: "memory");
        if (c + 1 < cend) {                  // prefetch a full iteration ahead
            stageV(cur ^ 1, c + 1);
            loadK(c + 1, kfn);
        }

        // ---- bias from precomputed packed indices + paired-head u32 lookups ----
        float biasr[2][4];
#pragma unroll
        for (int r = 0; r < 4; r++) {
            const unsigned u  = Pk[(quad * 4 + r) * 178 + (c - cbeg) * 16 + l16];
            const unsigned dc = u & 0xFFu;
            const unsigned ii = u >> 8;
            const unsigned du = *(const unsigned*)&Db[dc * 18 + hh0];
            const unsigned tu = *(const unsigned*)&Tt[ii * 18 + hh0];
            union { unsigned x; float f; } a0, a1, b0, b1;
            a0.x = du << 16; a1.x = du & 0xFFFF0000u;
            b0.x = tu << 16; b1.x = tu & 0xFFFF0000u;
            biasr[0][r] = a0.f + b0.f;
            biasr[1][r] = a1.f + b1.f;
        }

        // ---- V B-fragments via hardware transpose read (quads 0,1 = real keys) ----
        u32x2 raw[2][4];
        if (quad < 2) {
#pragma unroll
            for (int h = 0; h < 2; h++) {
                const unsigned va =
                    (unsigned)(uintptr_t)&Vc[cur][(hh0 + h) * 512 + quad * 256 + l16];
#pragma unroll
                for (int r = 0; r < 4; r++)
                    asm volatile("ds_read_b64_tr_b16 %0, %1 offset:%2"
                                 : "=v"(raw[h][r]) : "v"(va), "n"(r * 128));
            }
        }
        asm volatile("s_waitcnt lgkmcnt(0)" ::: "memory");
        __builtin_amdgcn_sched_barrier(0);   // rule 18: keep uses below the wait

        bf16x8 vfr[2][2] = {};               // quads 2,3 must be zero (K-padding)
        if (quad < 2) {
#pragma unroll
            for (int h = 0; h < 2; h++) {
                u32x4 w0, w1;
#pragma unroll
                for (int r = 0; r < 4; r++) {
                    // raw.x = (k, k) lo|hi cols l16,l16+16 ; raw.y = same for k+1
                    w0[r] = __builtin_amdgcn_perm(raw[h][r].y, raw[h][r].x, 0x05040100u);
                    w1[r] = __builtin_amdgcn_perm(raw[h][r].y, raw[h][r].x, 0x07060302u);
                }
                union { u32x4 u; bf16x8 s; } cv0, cv1;
                cv0.u = w0; cv1.u = w1;
                vfr[h][0] = cv0.s;           // cols l16      (tt=0)
                vfr[h][1] = cv1.s;           // cols l16+16   (tt=1)
            }
        }

        __builtin_amdgcn_s_setprio(1);
#pragma unroll
        for (int h = 0; h < 2; h++) {
            f32x4 s = __builtin_amdgcn_mfma_f32_16x16x32_bf16(
                qf[h], kf[h], (f32x4){0.f, 0.f, 0.f, 0.f}, 0, 0, 0);
            float pv[4];
#pragma unroll
            for (int r = 0; r < 4; r++) {
                float sv = s[r] * scale + biasr[h][r];
                sv = fminf(sv, 20.f);
                pv[r] = __expf(sv);
                lsum[h][r] += pv[r];
                Pb[wave * 640 + (quad * 4 + r) * 40 + l16] = f2bf(pv[r]);
            }
            const bf16x8 pf = *(const bf16x8*)&Pb[wave * 640 + l16 * 40 + quad * 8];
            O[h][0] = __builtin_amdgcn_mfma_f32_16x16x32_bf16(pf, vfr[h][0], O[h][0], 0, 0, 0);
            O[h][1] = __builtin_amdgcn_mfma_f32_16x16x32_bf16(pf, vfr[h][1], O[h][1], 0, 0, 0);
        }
        __builtin_amdgcn_s_setprio(0);

        kf[0] = kfn[0]; kf[1] = kfn[1];
        cur ^= 1;
    }

    const size_t poff = (size_t)part * 4096;
#pragma unroll
    for (int h = 0; h < 2; h++) {
        const int hh = hh0 + h;
#pragma unroll
        for (int m = 1; m < 16; m <<= 1)
#pragma unroll
            for (int r = 0; r < 4; r++) lsum[h][r] += __shfl_xor(lsum[h][r], m);
#pragma unroll
        for (int r = 0; r < 4; r++) {
            const size_t row = (size_t)(b * NN + q0 + quad * 4 + r);
#pragma unroll
            for (int tt = 0; tt < 2; tt++)
                O_part[(poff + row) * DD + hh * DH + tt * 16 + l16] = f2bf(O[h][tt][r]);
            if (l16 == 0) l_part[(poff + row) * NH + hh] = lsum[h][r];
        }
    }
}

extern "C" void kernel_launch(void* const* d_in, const int* in_sizes, int n_in,
                              void* d_out, int out_size, void* d_ws, size_t ws_size,
                              hipStream_t stream) {
    const float* x      = (const float*)d_in[0];
    const int*   dist   = (const int*)d_in[1];
    const float* dist3d = (const float*)d_in[2];
    const float* n1g    = (const float*)d_in[3];
    const float* n1b    = (const float*)d_in[4];
    const float* win    = (const float*)d_in[5];
    const float* bin    = (const float*)d_in[6];
    const float* wo     = (const float*)d_in[7];
    const float* bo     = (const float*)d_in[8];
    const float* demb   = (const float*)d_in[9];
    const float* rbfw   = (const float*)d_in[10];
    const float* rbfb   = (const float*)d_in[11];
    const float* n2g    = (const float*)d_in[12];
    const float* n2b    = (const float*)d_in[13];
    const float* w1     = (const float*)d_in[14];
    const float* b1     = (const float*)d_in[15];
    const float* w2     = (const float*)d_in[16];
    const float* b2     = (const float*)d_in[17];

    // workspace. Opart region (16 MB) is reused by mid_bf (ffn1 output) since
    // O_part+l_part are dead after gemm_op, which runs before ffn1.
    char* p = (char*)d_ws;
    short* h_bf   = (short*)p; p += (size_t)4096 * 512 * 2;
    short* qkv_bf = (short*)p; p += (size_t)4096 * 1536 * 2;
    float* hres   = (float*)p; p += (size_t)4096 * 512 * 4;
    short* h2_bf  = (short*)p; p += (size_t)4096 * 512 * 2;
    short* win_bf = (short*)p; p += (size_t)1536 * 512 * 2;
    short* wo_bf  = (short*)p; p += (size_t)512 * 512 * 2;
    short* w1_bf  = (short*)p; p += (size_t)2048 * 512 * 2;
    short* w2_bf  = (short*)p; p += (size_t)512 * 2048 * 2;
    short* Tg     = (short*)p; p += (size_t)8192;  // 194*16 bf16 = 6208 B
    short* O_part = (short*)p;
    short* mid_bf = (short*)p;  // overlays O_part region
    p += (size_t)4096 * 2048 * 2;
    float* l_part = (float*)p; p += (size_t)3 * 4096 * 16 * 4;

    const int M = BB * NN;  // 4096

    cvt_weights<<<dim3(1024, 5), 256, 0, stream>>>(
        win, wo, w1, w2, win_bf, wo_bf, w1_bf, w2_bf, rbfw, rbfb, Tg,
        1536 * 512, 512 * 512, 2048 * 512, 512 * 2048);
    ln_kernel<<<M, 256, 0, stream>>>(x, n1g, n1b, h_bf);
    // 128x128 tiles for the two big-N GEMMs (m93/m97 ladder: 64-row tile leaves
    // ~2x on the table); grids stay >=384 blocks so all CUs are covered.
    gemm_bf16<128, false, false, true><<<dim3(12, 32), 256, 0, stream>>>(
        h_bf, win_bf, bin, nullptr, qkv_bf, M, TD, DD);
    attn_mfma<<<768, 512, 0, stream>>>(
        qkv_bf, dist, dist3d, demb, Tg, O_part, l_part);
    gemm_op<<<dim3(4, 64), 256, 0, stream>>>(
        O_part, l_part, wo_bf, bo, h_bf, hres);
    ln_kernel<<<M, 256, 0, stream>>>(hres, n2g, n2b, h2_bf);
    gemm_bf16<128, true, false, true><<<dim3(16, 32), 256, 0, stream>>>(
        h2_bf, w1_bf, b1, nullptr, mid_bf, M, 2048, DD);
    // ffn2: N=512 -> keep 64-row tile so grid stays at 256 blocks
    gemm_bf16<64, false, true, false><<<dim3(4, 64), 256, 0, stream>>>(
        mid_bf, w2_bf, b2, hres, (float*)d_out, M, DD, 2048);
}

// Round 2
// 239.444 us; speedup vs baseline: 1.0537x; 1.0458x over previous
//
#include <hip/hip_runtime.h>
#include <hip/hip_bf16.h>
#include <math.h>

#define BB 8
#define NN 512
#define DD 512
#define NH 16
#define DH 32
#define TD 1536
#define NG 32
#define MAXD 128

typedef __attribute__((ext_vector_type(8))) short bf16x8;
typedef __attribute__((ext_vector_type(4))) float f32x4;
typedef __attribute__((ext_vector_type(2))) unsigned int u32x2;
typedef __attribute__((ext_vector_type(4))) unsigned int u32x4;

__device__ inline short f2bf(float x) {
    __hip_bfloat16 h = __float2bfloat16(x);
    return *reinterpret_cast<short*>(&h);
}
__device__ inline float bf2f(short x) {
    union { unsigned u; float f; } c;
    c.u = ((unsigned)(unsigned short)x) << 16;
    return c.f;
}
// v_cvt_pk_bf16_f32: lo16 <- src0, hi16 <- src1 (RNE). No builtin on gfx950.
__device__ inline unsigned cvt_pk_bf16(float lo, float hi) {
    unsigned r;
    asm("v_cvt_pk_bf16_f32 %0, %1, %2" : "=v"(r) : "v"(lo), "v"(hi));
    return r;
}
__device__ inline float exp2fast(float x) {  // D = 2^S0
    float r;
    asm("v_exp_f32 %0, %1" : "=v"(r) : "v"(x));
    return r;
}

// async 16B global->LDS. lds dest must be WAVE-UNIFORM base; lane i lands at base + i*16.
__device__ inline void gld_lds16(const void* g, void* l) {
    __builtin_amdgcn_global_load_lds(
        (const __attribute__((address_space(1))) unsigned int*)g,
        (__attribute__((address_space(3))) unsigned int*)l, 16, 0, 0);
}

// ------- weight fp32 -> bf16 convert (4 arrays) + fused RBF bias table ------
// Table: 193 nodes on [0,20] (nearest-neighbor lookup; |f'|*delta/2 ~ 3e-3).
// Tg is pre-scaled by log2(e): attention softmax runs in exp2 domain.
__global__ __launch_bounds__(256) void cvt_weights(
    const float* __restrict__ s0, const float* __restrict__ s1,
    const float* __restrict__ s2, const float* __restrict__ s3,
    short* __restrict__ d0, short* __restrict__ d1,
    short* __restrict__ d2, short* __restrict__ d3,
    const float* __restrict__ rbfw, const float* __restrict__ rbfb,
    short* __restrict__ Tg,
    int n0, int n1, int n2, int n3) {
    if (blockIdx.y == 4) {
        if (blockIdx.x != 0) return;
        const float STEP  = 20.0f / 31.0f;
        const float COEFF = -0.5f / (STEP * STEP);
        for (int idx = threadIdx.x; idx < 194 * 16; idx += 256) {
            const int i = idx >> 4, h = idx & 15;
            const float x = fminf((float)i, 192.0f) * (20.0f / 192.0f);
            float acc = rbfb[h];
#pragma unroll
            for (int g = 0; g < NG; g++) {
                const float t = x - (float)g * STEP;
                acc += __expf(COEFF * t * t) * rbfw[h * NG + g];
            }
            Tg[idx] = f2bf(acc * 1.44269504088896f);
        }
        return;
    }
    const float* s; short* d; int n;
    switch (blockIdx.y) {
        case 0: s = s0; d = d0; n = n0; break;
        case 1: s = s1; d = d1; n = n1; break;
        case 2: s = s2; d = d2; n = n2; break;
        default: s = s3; d = d3; n = n3; break;
    }
    const int i = (blockIdx.x * 256 + threadIdx.x) * 4;
    if (i >= n) return;
    const float4 v = *(const float4*)(s + i);
    short4 o;
    o.x = f2bf(v.x); o.y = f2bf(v.y); o.z = f2bf(v.z); o.w = f2bf(v.w);
    *(short4*)(d + i) = o;
}

// ---------------- LayerNorm: bf16 out ----------------
__global__ __launch_bounds__(256) void ln_kernel(const float* __restrict__ x,
                                                 const float* __restrict__ g,
                                                 const float* __restrict__ b,
                                                 short* __restrict__ out_bf) {
    const int row = blockIdx.x;
    const int tid = threadIdx.x;
    const int wave = tid >> 6, lane = tid & 63;
    const float* xr = x + (size_t)row * DD;
    const float v0 = xr[tid], v1 = xr[tid + 256];
    float s = v0 + v1, q = v0 * v0 + v1 * v1;
#pragma unroll
    for (int m = 1; m < 64; m <<= 1) { s += __shfl_xor(s, m); q += __shfl_xor(q, m); }
    __shared__ float ps[8];
    if (lane == 0) { ps[wave] = s; ps[wave + 4] = q; }
    __syncthreads();
    s = ps[0] + ps[1] + ps[2] + ps[3];
    q = ps[4] + ps[5] + ps[6] + ps[7];
    const float mean = s * (1.0f / DD);
    const float var  = q * (1.0f / DD) - mean * mean;
    const float rs   = rsqrtf(var + 1e-5f);
    out_bf[(size_t)row * DD + tid]       = f2bf((v0 - mean) * rs * g[tid] + b[tid]);
    out_bf[(size_t)row * DD + tid + 256] = f2bf((v1 - mean) * rs * g[tid + 256] + b[tid + 256]);
}

// ------- bf16 MFMA GEMM, double-buffered: C = A @ W^T + bias (+gelu)(+res) --
// RESMODE: 0 = none, 1 = fp32 residual, 2 = bf16 residual
template <int TM, bool GELU, int RESMODE, bool OUTBF>
__global__ __launch_bounds__(256) void gemm_bf16(
    const short* __restrict__ A, const short* __restrict__ Bw,
    const float* __restrict__ bias, const void* __restrict__ res,
    void* __restrict__ Cout, int M, int Nout, int K) {
    const int MI = TM / 32;
    const int bm = blockIdx.y * TM;
    const int bn = blockIdx.x * 128;
    const int tid  = threadIdx.x;
    const int wave = tid >> 6;
    const int lane = tid & 63;
    const int l16  = lane & 15;
    const int quad = lane >> 4;
    const int wr = (wave >> 1) * (TM / 2);
    const int wc = (wave & 1) * 64;

    __shared__ short As[2][TM * 32];
    __shared__ short Bs[2][128 * 32];

    f32x4 acc[MI][4];
#pragma unroll
    for (int i = 0; i < MI; i++)
#pragma unroll
        for (int j = 0; j < 4; j++) acc[i][j] = (f32x4){0.f, 0.f, 0.f, 0.f};

    auto stage = [&](int buf, int k0) {
        const short* Ab = A + (size_t)bm * K + k0;
        const short* Bb = Bw + (size_t)bn * K + k0;
#pragma unroll
        for (int j = 0; j < TM / 64; j++) {
            const int idx = j * 256 + wave * 64 + lane;
            gld_lds16(Ab + (size_t)(idx >> 2) * K + (idx & 3) * 8,
                      &As[buf][(size_t)(j * 256 + wave * 64) * 8]);
        }
#pragma unroll
        for (int j = 0; j < 2; j++) {
            const int idx = j * 256 + wave * 64 + lane;
            gld_lds16(Bb + (size_t)(idx >> 2) * K + (idx & 3) * 8,
                      &Bs[buf][(size_t)(j * 256 + wave * 64) * 8]);
        }
    };
    auto compute = [&](int buf) {
        bf16x8 af[MI], bfr[4];
#pragma unroll
        for (int i = 0; i < MI; i++)
            af[i] = *(const bf16x8*)&As[buf][(wr + i * 16 + l16) * 32 + quad * 8];
#pragma unroll
        for (int j = 0; j < 4; j++)
            bfr[j] = *(const bf16x8*)&Bs[buf][(wc + j * 16 + l16) * 32 + quad * 8];
#pragma unroll
        for (int i = 0; i < MI; i++)
#pragma unroll
            for (int j = 0; j < 4; j++)
                acc[i][j] = __builtin_amdgcn_mfma_f32_16x16x32_bf16(af[i], bfr[j], acc[i][j], 0, 0, 0);
    };

    stage(0, 0);
    __syncthreads();
    int cur = 0;
    for (int k0 = 32; k0 < K; k0 += 32) {
        stage(cur ^ 1, k0);
        compute(cur);
        __syncthreads();
        cur ^= 1;
    }
    compute(cur);

#pragma unroll
    for (int i = 0; i < MI; i++) {
#pragma unroll
        for (int r = 0; r < 4; r++) {
            const int row = bm + wr + i * 16 + quad * 4 + r;
#pragma unroll
            for (int j = 0; j < 4; j++) {
                const int col = bn + wc + j * 16 + l16;
                float v = acc[i][j][r] + bias[col];
                if (GELU) v = 0.5f * v * (1.0f + erff(v * 0.70710678118654752f));
                if (RESMODE == 1) v += ((const float*)res)[(size_t)row * Nout + col];
                if (RESMODE == 2) v += bf2f(((const short*)res)[(size_t)row * Nout + col]);
                if (OUTBF) ((short*)Cout)[(size_t)row * Nout + col] = f2bf(v);
                else       ((float*)Cout)[(size_t)row * Nout + col] = v;
            }
        }
    }
}

// ---------------- MFMA flash attention, NO split-K, 32-key chunks -----------
// v3: 256 blocks (1/CU exactly), 8 waves x 2 heads, full-K=32 PV via k-slot
//     permutation: slot (quad,j) <-> k = (j<4 ? quad*4+j : 16+quad*4+j-4),
//     which is exactly what ds_read_b64_tr_b16 (stride-16-short gather:
//     addr,+16,+32,+48) delivers from [k][16]-short tiles.
//     - S^T stored to Pb[32k][16q] with 2 packed ds_write_b64/head (cvt_pk),
//       read back as A-fragment with 2 tr-reads/head: no perms, no zero-pad.
//     - V [32k][32d]/head: 4 tr-reads + 8 perms/head covers both tt halves.
//     - Pk[512k][16q]: one ds_read_b64 replaces 4 scalar index reads.
//     - exp2-domain softmax (tables pre-scaled by log2 e) -> v_exp_f32 direct.
//     - attn normalizes by lsum and writes O bf16; split-K combine gone.
__global__ __launch_bounds__(512, 2) void attn_mfma(
    const short* __restrict__ qkv,
    const int* __restrict__ dist,
    const float* __restrict__ dist3d,
    const float* __restrict__ demb,
    const short* __restrict__ Tg,
    short* __restrict__ Obf) {         // [4096][512] bf16 normalized
    const int blk  = blockIdx.x;
    const int b    = blk & 7;
    const int q0   = (blk >> 3) * 16;
    const int tid  = threadIdx.x;
    const int wave = tid >> 6;
    const int lane = tid & 63;
    const int l16  = lane & 15;
    const int quad = lane >> 4;
    const int hh0  = wave * 2;

    __shared__ short Vc[2][NH * 1024];       // 64 KB dbuf: per head [32k][32d]
    __shared__ short Pb[16 * 512];           // 16 KB: per (wave,head) [32k][16q]
    __shared__ short Tt[194 * 18];           // rbf NN table (*log2e), pad 18
    __shared__ short Db[128 * 18];           // dist_emb (*log2e), pad 18
    __shared__ unsigned short Pk[512 * 16];  // 16 KB: [k][q] packed dc|(ii<<8)

    for (int i = tid; i < 194 * 16; i += 512) Tt[(i >> 4) * 18 + (i & 15)] = Tg[i];
    for (int i = tid; i < 128 * 16; i += 512)
        Db[(i >> 4) * 18 + (i & 15)] = f2bf(demb[i] * 1.44269504088896f);
    {   // (dc, ii) precompute for all 16 q x 512 k, coalesced on k
        const size_t rb = ((size_t)(b * NN) + q0) * NN;
#pragma unroll
        for (int q = 0; q < 16; q++) {
            const size_t off = rb + (size_t)q * NN + tid;
            int dc = dist[off];
            dc = min(max(dc, 0), MAXD - 1);
            int ii = (int)(dist3d[off] * 9.6f + 0.5f);  // 192/20
            ii = min(ii, 192);
            Pk[tid * 16 + q] = (unsigned short)(dc | (ii << 8));
        }
    }

    const float scale = 0.17677669529663687f * 1.44269504088896f;  // /sqrt(32)*log2e
    bf16x8 qf[2];
#pragma unroll
    for (int h = 0; h < 2; h++)
        qf[h] = *(const bf16x8*)(qkv + (size_t)(b * NN + q0 + l16) * TD + (hh0 + h) * DH + quad * 8);

    f32x4 O[2][2];
    float lsum[2][4];
#pragma unroll
    for (int h = 0; h < 2; h++) {
#pragma unroll
        for (int tt = 0; tt < 2; tt++) O[h][tt] = (f32x4){0.f, 0.f, 0.f, 0.f};
#pragma unroll
        for (int r = 0; r < 4; r++) lsum[h][r] = 0.f;
    }

    __syncthreads();  // tables + Pk visible; the only barrier.

    const int sk = lane >> 2;
    const int sc = lane & 3;

    auto stageV = [&](int buf, int c) {
        const size_t rowb = (size_t)(b * NN + c * 32 + sk) * TD + 2 * DD + sc * 8;
#pragma unroll
        for (int h = 0; h < 2; h++) {
            short* dst = &Vc[buf][(hh0 + h) * 1024];
            gld_lds16(qkv + rowb + (hh0 + h) * DH, dst);
            gld_lds16(qkv + rowb + (size_t)16 * TD + (hh0 + h) * DH, dst + 512);
        }
    };
    auto loadK = [&](int c, bf16x8 (*kd)[2]) {
#pragma unroll
        for (int h = 0; h < 2; h++) {
            const short* base =
                qkv + (size_t)(b * NN + c * 32 + l16) * TD + DD + (hh0 + h) * DH + quad * 8;
            kd[h][0] = *(const bf16x8*)base;
            kd[h][1] = *(const bf16x8*)(base + 16 * TD);
        }
    };

    bf16x8 kf[2][2], kfn[2][2];
    stageV(0, 0);
    loadK(0, kf);
    int cur = 0;

    for (int c = 0; c < 16; c++) {  // 16 chunks of 32 keys
        asm volatile("" ::: "memory");
        __builtin_amdgcn_s_waitcnt(0x0F70);  // vmcnt(0): V(c) in LDS, kf(c) in regs
        asm volatile("" ::: "memory");

        // V tr reads for chunk c (only need Vc[cur]) — issue early
        u32x2 vraw[2][4];
#pragma unroll
        for (int h = 0; h < 2; h++) {
            const unsigned va =
                (unsigned)(uintptr_t)&Vc[cur][(hh0 + h) * 1024 + quad * 128 + l16];
            asm volatile("ds_read_b64_tr_b16 %0, %1 offset:0"    : "=v"(vraw[h][0]) : "v"(va));
            asm volatile("ds_read_b64_tr_b16 %0, %1 offset:128"  : "=v"(vraw[h][1]) : "v"(va));
            asm volatile("ds_read_b64_tr_b16 %0, %1 offset:1024" : "=v"(vraw[h][2]) : "v"(va));
            asm volatile("ds_read_b64_tr_b16 %0, %1 offset:1152" : "=v"(vraw[h][3]) : "v"(va));
        }

        if (c + 1 < 16) {  // prefetch a full chunk ahead
            stageV(cur ^ 1, c + 1);
            loadK(c + 1, kfn);
        }

        // ---- QK^T + bias + exp2 softmax, both 16-key halves ----
#pragma unroll
        for (int half = 0; half < 2; half++) {
            const ushort4 pk4 =
                *(const ushort4*)&Pk[(unsigned)((c * 32 + half * 16 + l16) * 16 + quad * 4)];
            const unsigned short pe[4] = {pk4.x, pk4.y, pk4.z, pk4.w};
            float bb[2][4];
#pragma unroll
            for (int r = 0; r < 4; r++) {
                const unsigned u  = pe[r];
                const unsigned dc = u & 0xFFu;
                const unsigned ii = u >> 8;
                const unsigned du = *(const unsigned*)&Db[dc * 18 + hh0];
                const unsigned tu = *(const unsigned*)&Tt[ii * 18 + hh0];
                union { unsigned x; float f; } a0, a1, b0, b1;
                a0.x = du << 16; a1.x = du & 0xFFFF0000u;
                b0.x = tu << 16; b1.x = tu & 0xFFFF0000u;
                bb[0][r] = a0.f + b0.f;
                bb[1][r] = a1.f + b1.f;
            }
#pragma unroll
            for (int h = 0; h < 2; h++) {
                f32x4 s = __builtin_amdgcn_mfma_f32_16x16x32_bf16(
                    qf[h], kf[h][half], (f32x4){0.f, 0.f, 0.f, 0.f}, 0, 0, 0);
                float pv[4];
#pragma unroll
                for (int r = 0; r < 4; r++) {
                    float sv = s[r] * scale + bb[h][r];
                    sv = fminf(sv, 28.853901f);  // 20*log2e
                    pv[r] = exp2fast(sv);
                    lsum[h][r] += pv[r];
                }
                u32x2 w;
                w[0] = cvt_pk_bf16(pv[0], pv[1]);
                w[1] = cvt_pk_bf16(pv[2], pv[3]);
                // S^T: Pb[k][q], k = half*16+l16, q = quad*4..+3 (contiguous)
                *(u32x2*)&Pb[(wave * 2 + h) * 512 + (half * 16 + l16) * 16 + quad * 4] = w;
            }
        }

        asm volatile("" ::: "memory");
        asm volatile("s_waitcnt lgkmcnt(0)" ::: "memory");  // Pb writes + vraw done
        __builtin_amdgcn_sched_barrier(0);

        // P A-fragments: tr-read of [32k][16q] tile; k-map matches V's
        u32x2 praw[2][2];
#pragma unroll
        for (int h = 0; h < 2; h++) {
            const unsigned pa =
                (unsigned)(uintptr_t)&Pb[(wave * 2 + h) * 512 + quad * 64 + l16];
            asm volatile("ds_read_b64_tr_b16 %0, %1 offset:0"   : "=v"(praw[h][0]) : "v"(pa));
            asm volatile("ds_read_b64_tr_b16 %0, %1 offset:512" : "=v"(praw[h][1]) : "v"(pa));
        }
        asm volatile("s_waitcnt lgkmcnt(0)" ::: "memory");
        __builtin_amdgcn_sched_barrier(0);

        __builtin_amdgcn_s_setprio(1);
#pragma unroll
        for (int h = 0; h < 2; h++) {
            union { u32x4 u; bf16x8 s; } pf, v0, v1;
            pf.u = (u32x4){praw[h][0][0], praw[h][0][1], praw[h][1][0], praw[h][1][1]};
#pragma unroll
            for (int r = 0; r < 4; r++) {
                v0.u[r] = __builtin_amdgcn_perm(vraw[h][r][1], vraw[h][r][0], 0x05040100u);
                v1.u[r] = __builtin_amdgcn_perm(vraw[h][r][1], vraw[h][r][0], 0x07060302u);
            }
            O[h][0] = __builtin_amdgcn_mfma_f32_16x16x32_bf16(pf.s, v0.s, O[h][0], 0, 0, 0);
            O[h][1] = __builtin_amdgcn_mfma_f32_16x16x32_bf16(pf.s, v1.s, O[h][1], 0, 0, 0);
        }
        __builtin_amdgcn_s_setprio(0);

#pragma unroll
        for (int h = 0; h < 2; h++) { kf[h][0] = kfn[h][0]; kf[h][1] = kfn[h][1]; }
        cur ^= 1;
    }

    // epilogue: reduce lsum over the 16-lane group, normalize, write bf16 O
#pragma unroll
    for (int h = 0; h < 2; h++) {
        const int hh = hh0 + h;
#pragma unroll
        for (int m = 1; m < 16; m <<= 1)
#pragma unroll
            for (int r = 0; r < 4; r++) lsum[h][r] += __shfl_xor(lsum[h][r], m);
#pragma unroll
        for (int r = 0; r < 4; r++) {
            const float rl = 1.0f / lsum[h][r];
            const size_t row = (size_t)(b * NN + q0 + quad * 4 + r);
#pragma unroll
            for (int tt = 0; tt < 2; tt++)
                Obf[row * DD + hh * DH + tt * 16 + l16] = f2bf(O[h][tt][r] * rl);
        }
    }
}

extern "C" void kernel_launch(void* const* d_in, const int* in_sizes, int n_in,
                              void* d_out, int out_size, void* d_ws, size_t ws_size,
                              hipStream_t stream) {
    const float* x      = (const float*)d_in[0];
    const int*   dist   = (const int*)d_in[1];
    const float* dist3d = (const float*)d_in[2];
    const float* n1g    = (const float*)d_in[3];
    const float* n1b    = (const float*)d_in[4];
    const float* win    = (const float*)d_in[5];
    const float* bin    = (const float*)d_in[6];
    const float* wo     = (const float*)d_in[7];
    const float* bo     = (const float*)d_in[8];
    const float* demb   = (const float*)d_in[9];
    const float* rbfw   = (const float*)d_in[10];
    const float* rbfb   = (const float*)d_in[11];
    const float* n2g    = (const float*)d_in[12];
    const float* n2b    = (const float*)d_in[13];
    const float* w1     = (const float*)d_in[14];
    const float* b1     = (const float*)d_in[15];
    const float* w2     = (const float*)d_in[16];
    const float* b2     = (const float*)d_in[17];

    // workspace. o_bf region is reused by mid_bf (ffn1 output) since o_bf is
    // dead after the out-projection, which runs before ffn1.
    char* p = (char*)d_ws;
    short* h_bf   = (short*)p; p += (size_t)4096 * 512 * 2;
    short* qkv_bf = (short*)p; p += (size_t)4096 * 1536 * 2;
    float* hres   = (float*)p; p += (size_t)4096 * 512 * 4;
    short* h2_bf  = (short*)p; p += (size_t)4096 * 512 * 2;
    short* win_bf = (short*)p; p += (size_t)1536 * 512 * 2;
    short* wo_bf  = (short*)p; p += (size_t)512 * 512 * 2;
    short* w1_bf  = (short*)p; p += (size_t)2048 * 512 * 2;
    short* w2_bf  = (short*)p; p += (size_t)512 * 2048 * 2;
    short* Tg     = (short*)p; p += (size_t)8192;  // 194*16 bf16 = 6208 B
    short* o_bf   = (short*)p;
    short* mid_bf = (short*)p;  // overlays o_bf region
    p += (size_t)4096 * 2048 * 2;

    const int M = BB * NN;  // 4096

    cvt_weights<<<dim3(1024, 5), 256, 0, stream>>>(
        win, wo, w1, w2, win_bf, wo_bf, w1_bf, w2_bf, rbfw, rbfb, Tg,
        1536 * 512, 512 * 512, 2048 * 512, 512 * 2048);
    ln_kernel<<<M, 256, 0, stream>>>(x, n1g, n1b, h_bf);
    gemm_bf16<128, false, 0, true><<<dim3(12, 32), 256, 0, stream>>>(
        h_bf, win_bf, bin, nullptr, qkv_bf, M, TD, DD);
    attn_mfma<<<256, 512, 0, stream>>>(
        qkv_bf, dist, dist3d, demb, Tg, o_bf);
    gemm_bf16<64, false, 2, false><<<dim3(4, 64), 256, 0, stream>>>(
        o_bf, wo_bf, bo, h_bf, hres, M, DD, DD);
    ln_kernel<<<M, 256, 0, stream>>>(hres, n2g, n2b, h2_bf);
    gemm_bf16<128, true, 0, true><<<dim3(16, 32), 256, 0, stream>>>(
        h2_bf, w1_bf, b1, nullptr, mid_bf, M, 2048, DD);
    gemm_bf16<64, false, 1, false><<<dim3(4, 64), 256, 0, stream>>>(
        mid_bf, w2_bf, b2, hres, (float*)d_out, M, DD, 2048);
}